// Round 12
// baseline (310.301 us; speedup 1.0000x reference)
//
#include <hip/hip_runtime.h>
#include <math.h>

#define NB 4096
#define NT 2048
#define VM 256
#define VT 128
#define NOUT 1158
#define EPSF 1e-9f

__device__ __forceinline__ void write_cat(float* orow, int base, int V, int tid,
                                          float cnt, float sv, float sv2,
                                          float* s_distinct, int slot) {
    const float ecnt = (tid == 0) ? 0.f : cnt;   // category 0 masked
    orow[base + tid] = ecnt;
    orow[base + V + tid] = sv / (ecnt + EPSF);
    float av = sv2 - (sv * sv) / (ecnt + EPSF);
    av = av < 0.f ? 0.f : av;
    float dn = ecnt - 1.f; dn = dn < 0.f ? 0.f : dn;
    orow[base + 2 * V + tid] = sqrtf(av / (dn + EPSF));
    const unsigned long long bm = __ballot(ecnt > 0.f);
    if ((tid & 63) == 0) atomicAdd(&s_distinct[slot], (float)__popcll(bm));
}

__device__ __forceinline__ void write_scalars(float* orow, int tid, int row,
                                              const int* seq_lens,
                                              float tot_sum, float tot_sum2,
                                              const float* s_distinct) {
    if (tid == 0) {
        const float sl = (float)seq_lens[row];
        const float mean = tot_sum / (sl + EPSF);
        float a = tot_sum2 - (tot_sum * tot_sum) / (sl + EPSF);
        a = a < 0.f ? 0.f : a;
        float dn = sl - 1.f; dn = dn < 0.f ? 0.f : dn;
        orow[0] = sl;
        orow[1] = tot_sum;
        orow[2] = mean;
        orow[3] = sqrtf(a / (dn + EPSF));
        orow[4 + 3 * VM + 3 * VT]     = s_distinct[0];
        orow[4 + 3 * VM + 3 * VT + 1] = s_distinct[1];
    }
}

// element transform shared by all variants
__device__ __forceinline__ void elem_val(float a, float& v, float& v2) {
    v = copysignf(expm1f(fabsf(a)), a);
    v2 = v * v;
}

// ---------------- Variant A: 6x f32 LDS atomics (control) ----------------
__global__ __launch_bounds__(256) void agg_feature_a(
    const float* __restrict__ amount, const int* __restrict__ mcc,
    const int* __restrict__ trt, const int* __restrict__ seq_lens,
    float* __restrict__ out, int row0)
{
    const int row = blockIdx.x + row0;
    const int tid = threadIdx.x;

    __shared__ float s_cnt_m[VM], s_sv_m[VM], s_sv2_m[VM];
    __shared__ float s_cnt_t[VT], s_sv_t[VT], s_sv2_t[VT];
    __shared__ float s_part[8];
    __shared__ float s_distinct[2];

    s_cnt_m[tid] = 0.f; s_sv_m[tid] = 0.f; s_sv2_m[tid] = 0.f;
    if (tid < VT) { s_cnt_t[tid] = 0.f; s_sv_t[tid] = 0.f; s_sv2_t[tid] = 0.f; }
    if (tid < 2)  { s_distinct[tid] = 0.f; }
    __syncthreads();

    const float4* a4 = (const float4*)(amount + (size_t)row * NT);
    const int4*   m4 = (const int4*)(mcc    + (size_t)row * NT);
    const int4*   t4 = (const int4*)(trt    + (size_t)row * NT);

    float lsum = 0.f, lsum2 = 0.f;
    #pragma unroll
    for (int it = 0; it < NT / (256 * 4); ++it) {
        const int i = it * 256 + tid;
        const float4 av = a4[i];
        const int4   mv = m4[i];
        const int4   tv = t4[i];
        const float va[4] = {av.x, av.y, av.z, av.w};
        const int   mi[4] = {mv.x, mv.y, mv.z, mv.w};
        const int   ti[4] = {tv.x, tv.y, tv.z, tv.w};
        #pragma unroll
        for (int j = 0; j < 4; ++j) {
            float v, v2; elem_val(va[j], v, v2);
            lsum += v; lsum2 += v2;
            int m = mi[j]; m = m < 0 ? 0 : (m > VM - 1 ? VM - 1 : m);
            int t = ti[j]; t = t < 0 ? 0 : (t > VT - 1 ? VT - 1 : t);
            atomicAdd(&s_cnt_m[m], 1.f);
            atomicAdd(&s_sv_m[m],  v);
            atomicAdd(&s_sv2_m[m], v2);
            atomicAdd(&s_cnt_t[t], 1.f);
            atomicAdd(&s_sv_t[t],  v);
            atomicAdd(&s_sv2_t[t], v2);
        }
    }

    #pragma unroll
    for (int off = 32; off > 0; off >>= 1) {
        lsum  += __shfl_down(lsum,  off);
        lsum2 += __shfl_down(lsum2, off);
    }
    const int wave = tid >> 6;
    if ((tid & 63) == 0) { s_part[wave] = lsum; s_part[4 + wave] = lsum2; }
    __syncthreads();

    float tot_sum = 0.f, tot_sum2 = 0.f;
    if (tid == 0) {
        tot_sum  = s_part[0] + s_part[1] + s_part[2] + s_part[3];
        tot_sum2 = s_part[4] + s_part[5] + s_part[6] + s_part[7];
    }

    float* orow = out + (size_t)row * NOUT;
    write_cat(orow, 4, VM, tid, s_cnt_m[tid], s_sv_m[tid], s_sv2_m[tid], s_distinct, 0);
    if (tid < VT)
        write_cat(orow, 4 + 3 * VM, VT, tid, s_cnt_t[tid], s_sv_t[tid], s_sv2_t[tid], s_distinct, 1);
    __syncthreads();
    write_scalars(orow, tid, row, seq_lens, tot_sum, tot_sum2, s_distinct);
}

// ---------------- Variant C: 6x u32 integer fixed-point atomics ----------------
// sv as i32 @ 2^-8 (|sum|*256 <= ~9.6e8 < 2^31), sv2 as u32 @ 2^-8 (sum*256 <= ~8.6e8).
__global__ __launch_bounds__(256) void agg_feature_c(
    const float* __restrict__ amount, const int* __restrict__ mcc,
    const int* __restrict__ trt, const int* __restrict__ seq_lens,
    float* __restrict__ out, int row0)
{
    const int row = blockIdx.x + row0;
    const int tid = threadIdx.x;

    __shared__ unsigned s_cnt_m[VM], s_sv_m[VM], s_sv2_m[VM];
    __shared__ unsigned s_cnt_t[VT], s_sv_t[VT], s_sv2_t[VT];
    __shared__ float s_part[8];
    __shared__ float s_distinct[2];

    s_cnt_m[tid] = 0u; s_sv_m[tid] = 0u; s_sv2_m[tid] = 0u;
    if (tid < VT) { s_cnt_t[tid] = 0u; s_sv_t[tid] = 0u; s_sv2_t[tid] = 0u; }
    if (tid < 2)  { s_distinct[tid] = 0.f; }
    __syncthreads();

    const float4* a4 = (const float4*)(amount + (size_t)row * NT);
    const int4*   m4 = (const int4*)(mcc    + (size_t)row * NT);
    const int4*   t4 = (const int4*)(trt    + (size_t)row * NT);

    float lsum = 0.f, lsum2 = 0.f;
    #pragma unroll
    for (int it = 0; it < NT / (256 * 4); ++it) {
        const int i = it * 256 + tid;
        const float4 av = a4[i];
        const int4   mv = m4[i];
        const int4   tv = t4[i];
        const float va[4] = {av.x, av.y, av.z, av.w};
        const int   mi[4] = {mv.x, mv.y, mv.z, mv.w};
        const int   ti[4] = {tv.x, tv.y, tv.z, tv.w};
        #pragma unroll
        for (int j = 0; j < 4; ++j) {
            float v, v2; elem_val(va[j], v, v2);
            lsum += v; lsum2 += v2;
            int m = mi[j]; m = m < 0 ? 0 : (m > VM - 1 ? VM - 1 : m);
            int t = ti[j]; t = t < 0 ? 0 : (t > VT - 1 ? VT - 1 : t);

            const unsigned svf  = (unsigned)__float2int_rn(v  * 256.0f);
            const unsigned sv2f = (unsigned)__float2uint_rn(v2 * 256.0f);
            atomicAdd(&s_cnt_m[m], 1u);
            atomicAdd(&s_sv_m[m],  svf);
            atomicAdd(&s_sv2_m[m], sv2f);
            atomicAdd(&s_cnt_t[t], 1u);
            atomicAdd(&s_sv_t[t],  svf);
            atomicAdd(&s_sv2_t[t], sv2f);
        }
    }

    #pragma unroll
    for (int off = 32; off > 0; off >>= 1) {
        lsum  += __shfl_down(lsum,  off);
        lsum2 += __shfl_down(lsum2, off);
    }
    const int wave = tid >> 6;
    if ((tid & 63) == 0) { s_part[wave] = lsum; s_part[4 + wave] = lsum2; }
    __syncthreads();

    float tot_sum = 0.f, tot_sum2 = 0.f;
    if (tid == 0) {
        tot_sum  = s_part[0] + s_part[1] + s_part[2] + s_part[3];
        tot_sum2 = s_part[4] + s_part[5] + s_part[6] + s_part[7];
    }

    float* orow = out + (size_t)row * NOUT;
    write_cat(orow, 4, VM, tid, (float)s_cnt_m[tid],
              (float)(int)s_sv_m[tid] * (1.0f / 256.0f),
              (float)s_sv2_m[tid] * (1.0f / 256.0f), s_distinct, 0);
    if (tid < VT)
        write_cat(orow, 4 + 3 * VM, VT, tid, (float)s_cnt_t[tid],
                  (float)(int)s_sv_t[tid] * (1.0f / 256.0f),
                  (float)s_sv2_t[tid] * (1.0f / 256.0f), s_distinct, 1);
    __syncthreads();
    write_scalars(orow, tid, row, seq_lens, tot_sum, tot_sum2, s_distinct);
}

// ---------------- Variant D: per-wave privatized f32 histograms (4 copies) ----------------
__global__ __launch_bounds__(256) void agg_feature_d(
    const float* __restrict__ amount, const int* __restrict__ mcc,
    const int* __restrict__ trt, const int* __restrict__ seq_lens,
    float* __restrict__ out, int row0)
{
    const int row = blockIdx.x + row0;
    const int tid = threadIdx.x;
    const int wave = tid >> 6;

    // [copy][stat: 0=cnt 1=sv 2=sv2][cat: mcc 0..255, trt 256..383]
    __shared__ float s_h[4][3][VM + VT];
    __shared__ float s_part[8];
    __shared__ float s_distinct[2];

    float* hflat = &s_h[0][0][0];
    for (int k = tid; k < 4 * 3 * (VM + VT); k += 256) hflat[k] = 0.f;
    if (tid < 2) s_distinct[tid] = 0.f;
    __syncthreads();

    const float4* a4 = (const float4*)(amount + (size_t)row * NT);
    const int4*   m4 = (const int4*)(mcc    + (size_t)row * NT);
    const int4*   t4 = (const int4*)(trt    + (size_t)row * NT);

    float lsum = 0.f, lsum2 = 0.f;
    #pragma unroll
    for (int it = 0; it < NT / (256 * 4); ++it) {
        const int i = it * 256 + tid;
        const float4 av = a4[i];
        const int4   mv = m4[i];
        const int4   tv = t4[i];
        const float va[4] = {av.x, av.y, av.z, av.w};
        const int   mi[4] = {mv.x, mv.y, mv.z, mv.w};
        const int   ti[4] = {tv.x, tv.y, tv.z, tv.w};
        #pragma unroll
        for (int j = 0; j < 4; ++j) {
            float v, v2; elem_val(va[j], v, v2);
            lsum += v; lsum2 += v2;
            int m = mi[j]; m = m < 0 ? 0 : (m > VM - 1 ? VM - 1 : m);
            int t = ti[j]; t = t < 0 ? 0 : (t > VT - 1 ? VT - 1 : t);
            atomicAdd(&s_h[wave][0][m], 1.f);
            atomicAdd(&s_h[wave][1][m], v);
            atomicAdd(&s_h[wave][2][m], v2);
            atomicAdd(&s_h[wave][0][VM + t], 1.f);
            atomicAdd(&s_h[wave][1][VM + t], v);
            atomicAdd(&s_h[wave][2][VM + t], v2);
        }
    }

    #pragma unroll
    for (int off = 32; off > 0; off >>= 1) {
        lsum  += __shfl_down(lsum,  off);
        lsum2 += __shfl_down(lsum2, off);
    }
    if ((tid & 63) == 0) { s_part[wave] = lsum; s_part[4 + wave] = lsum2; }
    __syncthreads();

    float tot_sum = 0.f, tot_sum2 = 0.f;
    if (tid == 0) {
        tot_sum  = s_part[0] + s_part[1] + s_part[2] + s_part[3];
        tot_sum2 = s_part[4] + s_part[5] + s_part[6] + s_part[7];
    }

    float* orow = out + (size_t)row * NOUT;
    {
        const float cnt = s_h[0][0][tid] + s_h[1][0][tid] + s_h[2][0][tid] + s_h[3][0][tid];
        const float sv  = s_h[0][1][tid] + s_h[1][1][tid] + s_h[2][1][tid] + s_h[3][1][tid];
        const float sv2 = s_h[0][2][tid] + s_h[1][2][tid] + s_h[2][2][tid] + s_h[3][2][tid];
        write_cat(orow, 4, VM, tid, cnt, sv, sv2, s_distinct, 0);
    }
    if (tid < VT) {
        const int c = VM + tid;
        const float cnt = s_h[0][0][c] + s_h[1][0][c] + s_h[2][0][c] + s_h[3][0][c];
        const float sv  = s_h[0][1][c] + s_h[1][1][c] + s_h[2][1][c] + s_h[3][1][c];
        const float sv2 = s_h[0][2][c] + s_h[1][2][c] + s_h[2][2][c] + s_h[3][2][c];
        write_cat(orow, 4 + 3 * VM, VT, tid, cnt, sv, sv2, s_distinct, 1);
    }
    __syncthreads();
    write_scalars(orow, tid, row, seq_lens, tot_sum, tot_sum2, s_distinct);
}

extern "C" void kernel_launch(void* const* d_in, const int* in_sizes, int n_in,
                              void* d_out, int out_size, void* d_ws, size_t ws_size,
                              hipStream_t stream) {
    const float* amount   = (const float*)d_in[0];
    const int*   mcc      = (const int*)d_in[1];
    const int*   trt      = (const int*)d_in[2];
    const int*   seq_lens = (const int*)d_in[3];
    float* out = (float*)d_out;

    agg_feature_a<<<1366, 256, 0, stream>>>(amount, mcc, trt, seq_lens, out, 0);
    agg_feature_c<<<1365, 256, 0, stream>>>(amount, mcc, trt, seq_lens, out, 1366);
    agg_feature_d<<<1365, 256, 0, stream>>>(amount, mcc, trt, seq_lens, out, 2731);
}

// Round 15
// 293.999 us; speedup vs baseline: 1.0554x; 1.0554x over previous
//
#include <hip/hip_runtime.h>
#include <math.h>

#define NB 4096
#define NT 2048
#define VM 256
#define VT 128
#define NOUT 1158
#define EPSF 1e-9f

#define NTHREADS 192
#define NWAVES 3
#define NCOPIES 24            // 3 waves x 8 lane-groups
#define COPY_F4 385           // 385 float4 = 6160 B  (384 cats * 16B + 16B bank-stagger pad)
#define TOT_F4 (NCOPIES * COPY_F4)   // 9240 float4 = 147,840 B

// One block per row. Exclusive-ownership manual RMW histograms:
// copy id = wave*8 + (lane>>3); the 8 members of a lane-group serialize
// over 8 predicated rounds, so read-modify-write needs NO atomics.
__global__ __launch_bounds__(NTHREADS) void agg_rmw(
    const float* __restrict__ amount, const int* __restrict__ mcc,
    const int* __restrict__ trt, const int* __restrict__ seq_lens,
    float* __restrict__ out)
{
    const int row  = blockIdx.x;
    const int tid  = threadIdx.x;
    const int lane = tid & 63;
    const int wave = tid >> 6;

    __shared__ float4 s_h[TOT_F4];
    __shared__ float  s_part[2 * NWAVES];
    __shared__ float  s_distinct[2];

    for (int i = tid; i < TOT_F4; i += NTHREADS)
        s_h[i] = make_float4(0.f, 0.f, 0.f, 0.f);
    if (tid < 2) s_distinct[tid] = 0.f;
    __syncthreads();

    const float* arow = amount + (size_t)row * NT;
    const int*   mrow = mcc    + (size_t)row * NT;
    const int*   trow = trt    + (size_t)row * NT;

    const int copy_f4 = (wave * 8 + (lane >> 3)) * COPY_F4;

    float lsum = 0.f, lsum2 = 0.f;

    // prefetch iteration 0 (clamped, branchless -> hoistable loads)
    int cidx = tid;
    float a_c = arow[cidx];
    int   m_c = mrow[cidx];
    int   t_c = trow[cidx];

    // 2048 = 10*192 + 128  -> 11 iterations
    for (int it = 0; it < 11; ++it) {
        const int idx = it * NTHREADS + tid;
        const bool valid = idx < NT;

        // prefetch next (clamped; overlaps with the RMW chain below)
        int nidx = (it + 1) * NTHREADS + tid;
        nidx = nidx < NT ? nidx : NT - 1;
        const float a_n = arow[nidx];
        const int   m_n = mrow[nidx];
        const int   t_n = trow[nidx];

        float v  = copysignf(expm1f(fabsf(a_c)), a_c);
        float v2 = v * v;
        if (valid) { lsum += v; lsum2 += v2; }

        int m = m_c; m = m < 0 ? 0 : (m > VM - 1 ? VM - 1 : m);
        int t = t_c; t = t < 0 ? 0 : (t > VT - 1 ? VT - 1 : t);
        const int am = copy_f4 + m;        // float4 index of (cnt,sv,sv2,pad)
        const int at = copy_f4 + VM + t;

        #pragma unroll
        for (int r = 0; r < 8; ++r) {
            if (valid && (lane & 7) == r) {
                float4 hm = s_h[am];
                float4 ht = s_h[at];
                hm.x += 1.f; hm.y += v; hm.z += v2;
                ht.x += 1.f; ht.y += v; ht.z += v2;
                s_h[am] = hm;
                s_h[at] = ht;
            }
        }

        a_c = a_n; m_c = m_n; t_c = t_n;
    }

    // wave-reduce scalar sums
    #pragma unroll
    for (int off = 32; off > 0; off >>= 1) {
        lsum  += __shfl_down(lsum,  off);
        lsum2 += __shfl_down(lsum2, off);
    }
    if (lane == 0) { s_part[wave] = lsum; s_part[NWAVES + wave] = lsum2; }
    __syncthreads();

    float* orow = out + (size_t)row * NOUT;

    // epilogue: reduce 24 copies; 2 passes, contiguous (conflict-free) b128 reads
    #pragma unroll
    for (int pass = 0; pass < 2; ++pass) {
        const int cat = pass * NTHREADS + tid;       // 0..191 then 192..383
        float cnt = 0.f, sv = 0.f, sv2 = 0.f;
        #pragma unroll
        for (int c = 0; c < NCOPIES; ++c) {
            const float4 h = s_h[c * COPY_F4 + cat];
            cnt += h.x; sv += h.y; sv2 += h.z;
        }
        const float ecnt = (cat == 0 || cat == VM) ? 0.f : cnt;  // cat-0 of each vocab masked
        const float mean = sv / (ecnt + EPSF);
        float av = sv2 - (sv * sv) / (ecnt + EPSF);
        av = av < 0.f ? 0.f : av;
        float dn = ecnt - 1.f; dn = dn < 0.f ? 0.f : dn;
        const float stdv = sqrtf(av / (dn + EPSF));

        if (cat < VM) {
            orow[4 + cat]          = ecnt;
            orow[4 + VM + cat]     = mean;
            orow[4 + 2 * VM + cat] = stdv;
        } else {
            const int tc = cat - VM;
            const int base = 4 + 3 * VM;
            orow[base + tc]          = ecnt;
            orow[base + VT + tc]     = mean;
            orow[base + 2 * VT + tc] = stdv;
        }

        // distinct counts: pass0 cats are all mcc; pass1: wave0 -> mcc 192..255,
        // waves 1-2 -> trt 0..127 (trt cat0 masked at cat==VM above)
        const unsigned long long bm = __ballot(ecnt > 0.f);
        const int slot = (pass == 0 || wave == 0) ? 0 : 1;
        if (lane == 0) atomicAdd(&s_distinct[slot], (float)__popcll(bm));
    }
    __syncthreads();

    if (tid == 0) {
        const float tot  = s_part[0] + s_part[1] + s_part[2];
        const float tot2 = s_part[3] + s_part[4] + s_part[5];
        const float sl = (float)seq_lens[row];
        const float mean = tot / (sl + EPSF);
        float a = tot2 - (tot * tot) / (sl + EPSF);
        a = a < 0.f ? 0.f : a;
        float dn = sl - 1.f; dn = dn < 0.f ? 0.f : dn;
        orow[0] = sl;
        orow[1] = tot;
        orow[2] = mean;
        orow[3] = sqrtf(a / (dn + EPSF));
        orow[4 + 3 * VM + 3 * VT]     = s_distinct[0];
        orow[4 + 3 * VM + 3 * VT + 1] = s_distinct[1];
    }
}

extern "C" void kernel_launch(void* const* d_in, const int* in_sizes, int n_in,
                              void* d_out, int out_size, void* d_ws, size_t ws_size,
                              hipStream_t stream) {
    const float* amount   = (const float*)d_in[0];
    const int*   mcc      = (const int*)d_in[1];
    const int*   trt      = (const int*)d_in[2];
    const int*   seq_lens = (const int*)d_in[3];
    float* out = (float*)d_out;

    agg_rmw<<<NB, NTHREADS, 0, stream>>>(amount, mcc, trt, seq_lens, out);
}